// Round 1
// baseline (46.841 us; speedup 1.0000x reference)
//
#include <hip/hip_runtime.h>

// PatchBlender: out[b,0,:] = x[b,0,:]; for token=1..F*P:
//   t = (token-1)/P; out[b,token,e] = sum_f M[t,f] * x[b, 1+f*P+(token-1)%P, e]
// M is banded (3 taps centered at diag with DIAG_INDEX=1), so only f in
// {t-1,t,t+1} contribute. We read the actual weights from the input matrix so
// edge-row renormalization is reproduced exactly.

#define NFRAMES 16
#define NPATCH  196
#define EMBED   768
#define NBATCH  8
#define NTOKENS (NFRAMES * NPATCH + 1)   // 3137
#define E4      (EMBED / 4)              // 192 float4 per row

__global__ void __launch_bounds__(256)
patch_blender_kernel(const float4* __restrict__ x,
                     const float* __restrict__ M,
                     float4* __restrict__ out) {
    __shared__ float sM[NFRAMES * NFRAMES];
    if (threadIdx.x < NFRAMES * NFRAMES) sM[threadIdx.x] = M[threadIdx.x];
    __syncthreads();

    const int total  = NBATCH * NTOKENS * E4;      // 4,818,432 < 2^31
    const int stride = gridDim.x * blockDim.x;
    for (int idx = blockIdx.x * blockDim.x + threadIdx.x; idx < total; idx += stride) {
        int e4    = idx % E4;
        int rest  = idx / E4;
        int token = rest % NTOKENS;
        int b     = rest / NTOKENS;

        const float4* xb = x + (size_t)b * NTOKENS * E4;

        if (token == 0) {
            out[idx] = xb[e4];                      // cls token passthrough
            continue;
        }

        int t = (token - 1) / NPATCH;               // output frame index
        int center = token * E4 + e4;               // float4 index within batch

        float wc = sM[t * NFRAMES + t];
        float4 c = xb[center];
        float4 acc;
        acc.x = wc * c.x; acc.y = wc * c.y; acc.z = wc * c.z; acc.w = wc * c.w;

        if (t > 0) {
            float wl = sM[t * NFRAMES + (t - 1)];
            float4 l = xb[center - NPATCH * E4];
            acc.x += wl * l.x; acc.y += wl * l.y; acc.z += wl * l.z; acc.w += wl * l.w;
        }
        if (t < NFRAMES - 1) {
            float wr = sM[t * NFRAMES + (t + 1)];
            float4 r = xb[center + NPATCH * E4];
            acc.x += wr * r.x; acc.y += wr * r.y; acc.z += wr * r.z; acc.w += wr * r.w;
        }
        out[idx] = acc;
    }
}

extern "C" void kernel_launch(void* const* d_in, const int* in_sizes, int n_in,
                              void* d_out, int out_size, void* d_ws, size_t ws_size,
                              hipStream_t stream) {
    const float4* x = (const float4*)d_in[0];
    const float*  M = (const float*)d_in[1];
    float4* out = (float4*)d_out;

    const int total = NBATCH * NTOKENS * E4;
    int threads = 256;
    int blocks = (total + threads - 1) / threads;
    if (blocks > 2048) blocks = 2048;               // grid-stride the rest
    patch_blender_kernel<<<blocks, threads, 0, stream>>>(x, M, out);
}

// Round 2
// 28.021 us; speedup vs baseline: 1.6716x; 1.6716x over previous
//
#include <hip/hip_runtime.h>

// PatchBlender, column-per-thread formulation:
// out[b, 1+t*P+p, e] = wl[t]*x[b,1+(t-1)*P+p,e] + wc[t]*x[...t...] + wr[t]*x[...t+1...]
// Each thread owns one (b, p, e4) column across all 16 frames: 16 float4 loads,
// 16 float4 stores -> every input element fetched exactly once.
// Weights taken from the input smoothing_matrix (edge rows are renormalized there).

#define NFRAMES 16
#define NPATCH  196
#define EMBED   768
#define NBATCH  8
#define NTOKENS (NFRAMES * NPATCH + 1)   // 3137
#define E4      (EMBED / 4)              // 192 float4 per embed row
#define FSTRIDE (NPATCH * E4)            // float4 stride between frames

#define COL_TOTAL (NBATCH * NPATCH * E4) // 301,056 column threads
#define CLS_TOTAL (NBATCH * E4)          // 1,536 cls-copy threads

__global__ void __launch_bounds__(256)
patch_blender_col_kernel(const float4* __restrict__ x,
                         const float* __restrict__ M,
                         float4* __restrict__ out) {
    __shared__ float sWl[NFRAMES], sWc[NFRAMES], sWr[NFRAMES];
    if (threadIdx.x < NFRAMES) {
        int t = threadIdx.x;
        sWl[t] = (t > 0)           ? M[t * NFRAMES + t - 1] : 0.0f;
        sWc[t] =                     M[t * NFRAMES + t];
        sWr[t] = (t < NFRAMES - 1) ? M[t * NFRAMES + t + 1] : 0.0f;
    }
    __syncthreads();

    int idx = blockIdx.x * blockDim.x + threadIdx.x;

    if (idx < COL_TOTAL) {
        int e4   = idx % E4;
        int rest = idx / E4;
        int p    = rest % NPATCH;
        int b    = rest / NPATCH;

        // float4 index of frame 0's element in this column
        const size_t base = (size_t)b * NTOKENS * E4 + (size_t)(1 + p) * E4 + e4;

        float4 v[NFRAMES];
#pragma unroll
        for (int f = 0; f < NFRAMES; ++f)
            v[f] = x[base + (size_t)f * FSTRIDE];

#pragma unroll
        for (int t = 0; t < NFRAMES; ++t) {
            float wc = sWc[t];
            float4 c = v[t];
            float4 a;
            a.x = wc * c.x; a.y = wc * c.y; a.z = wc * c.z; a.w = wc * c.w;
            if (t > 0) {
                float wl = sWl[t];
                float4 l = v[t - 1];
                a.x += wl * l.x; a.y += wl * l.y; a.z += wl * l.z; a.w += wl * l.w;
            }
            if (t < NFRAMES - 1) {
                float wr = sWr[t];
                float4 r = v[t + 1];
                a.x += wr * r.x; a.y += wr * r.y; a.z += wr * r.z; a.w += wr * r.w;
            }
            out[base + (size_t)t * FSTRIDE] = a;
        }
    } else if (idx < COL_TOTAL + CLS_TOTAL) {
        int j  = idx - COL_TOTAL;
        int e4 = j % E4;
        int b  = j / E4;
        size_t o = (size_t)b * NTOKENS * E4 + e4;
        out[o] = x[o];                              // cls token passthrough
    }
}

extern "C" void kernel_launch(void* const* d_in, const int* in_sizes, int n_in,
                              void* d_out, int out_size, void* d_ws, size_t ws_size,
                              hipStream_t stream) {
    const float4* x = (const float4*)d_in[0];
    const float*  M = (const float*)d_in[1];
    float4* out = (float4*)d_out;

    const int total = COL_TOTAL + CLS_TOTAL;
    int threads = 256;
    int blocks = (total + threads - 1) / threads;   // 1182 blocks
    patch_blender_col_kernel<<<blocks, threads, 0, stream>>>(x, M, out);
}